// Round 3
// baseline (98.959 us; speedup 1.0000x reference)
//
#include <hip/hip_runtime.h>

#define NN 8192
#define DD 128
#define DEG 32
#define EE (NN*DEG)
#define AA 64
#define KP 136   // padded LDS K-stride in bf16 (272 B -> bank-conflict-free-ish)

using short8 = __attribute__((ext_vector_type(8))) short;
using f32x4  = __attribute__((ext_vector_type(4))) float;

__device__ __forceinline__ unsigned short f2bf(float x) {
    unsigned u = __builtin_bit_cast(unsigned, x);
    u += 0x7FFFu + ((u >> 16) & 1u);
    return (unsigned short)(u >> 16);
}
__device__ __forceinline__ float bf2f(unsigned short h) {
    unsigned u = ((unsigned)h) << 16;
    return __builtin_bit_cast(float, u);
}

// ---- ws layout (bytes) ----
// inv_src  0        1048576   int  [NN][DEG]  (src node per (dst,slot))
// nfbf     1048576  2097152   bf16 [NN][DD]
// aggbf    3145728  2097152   bf16 [NN][DD]
// node_sum 5242880  512       f32  [DD]
// W1bf     5243392  34816     bf16 [DD][KP]   (W_msg[:,0:128], zero-padded)
// W2bf     5278208  32768     bf16 [DD][DD]   (W_msg[:,128:256], dense)
// wibf     5310976  98304     bf16 [384][DD]
// whbf     5409280  98304     bf16 [384][DD]
// end      5507584

__global__ __launch_bounds__(256) void prep_kernel(
    const float* __restrict__ nf, const int* __restrict__ src_idx,
    const int* __restrict__ dst_idx,
    const float* __restrict__ W_msg, const float* __restrict__ w_ih,
    const float* __restrict__ w_hh,
    int* __restrict__ inv_src, unsigned short* __restrict__ nfbf,
    float* __restrict__ node_sum,
    unsigned short* __restrict__ W1bf, unsigned short* __restrict__ W2bf,
    unsigned short* __restrict__ wibf, unsigned short* __restrict__ whbf)
{
    const int idx = blockIdx.x * 256 + threadIdx.x;   // 0..EE-1 (262144)
    // edge scatter: slot j = e & 31 is unique per dst for this edge list
    {
        int d = dst_idx[idx];
        inv_src[d * DEG + (idx & 31)] = src_idx[idx];
    }
    // node features -> bf16 (4 elems/thread covers NN*DD exactly)
    {
        const float4 v = *(const float4*)&nf[(size_t)idx * 4];
        unsigned short h[4] = { f2bf(v.x), f2bf(v.y), f2bf(v.z), f2bf(v.w) };
        *(uint2*)&nfbf[(size_t)idx * 4] = *(uint2*)h;
    }
    if (idx < DD * KP) {
        int f = idx / KP, k = idx % KP;
        W1bf[idx] = (k < DD) ? f2bf(W_msg[f * 257 + k]) : (unsigned short)0;
    }
    if (idx < DD * DD) {
        int f = idx >> 7, k = idx & 127;
        W2bf[idx] = f2bf(W_msg[f * 257 + 128 + k]);
    }
    if (idx < 384 * DD) {
        wibf[idx] = f2bf(w_ih[idx]);
        whbf[idx] = f2bf(w_hh[idx]);
    }
    if (idx < DD) node_sum[idx] = 0.f;
}

// one block = 4 dst nodes (128 src rows); src GEMM + replicated dst GEMM + fused relu/agg
__global__ __launch_bounds__(256) void msg_agg_kernel(
    const unsigned short* __restrict__ nfbf, const float* __restrict__ efeat,
    const int* __restrict__ inv_src,
    const unsigned short* __restrict__ W1bf, const unsigned short* __restrict__ W2bf,
    const float* __restrict__ W_msg, const float* __restrict__ b_msg,
    unsigned short* __restrict__ aggbf)
{
    __shared__ __align__(16) unsigned short Asz[128 * KP];
    __shared__ __align__(16) unsigned short Bsz[128 * KP];
    __shared__ int   s_src[128];
    __shared__ float s_ef[128];

    const int t = threadIdx.x;
    const int blk = blockIdx.x;

    {   // W1 -> LDS (34816 B = 2176 uint4), L2-hot
        const uint4* g4 = (const uint4*)W1bf;
        uint4* l4 = (uint4*)Bsz;
        for (int i = t; i < 2176; i += 256) l4[i] = g4[i];
    }
    if (t < 128) {
        int s = inv_src[blk * 128 + t];          // coalesced
        s_src[t] = s;
        int d = blk * 4 + (t >> 5);
        s_ef[t] = efeat[(size_t)s * NN + d];
    }
    __syncthreads();

    // A stage: gather 128 bf16 rows, 16B per thread, 8 iters
    for (int it = 0; it < 8; ++it) {
        int row = it * 16 + (t >> 4);
        int ch = t & 15;
        uint4 v = *(const uint4*)&nfbf[(size_t)s_src[row] * DD + ch * 8];
        *(uint4*)&Asz[row * KP + ch * 8] = v;
    }
    __syncthreads();

    const int w = t >> 6, l = t & 63, p = l & 15, q = l >> 4;
    const int d = blk * 4 + w;
    const unsigned short* drow = &nfbf[(size_t)d * DD];

    f32x4 accS[2][8];
    f32x4 accD[8];
    const f32x4 z4 = {0.f, 0.f, 0.f, 0.f};
#pragma unroll
    for (int n = 0; n < 8; ++n) { accS[0][n] = z4; accS[1][n] = z4; accD[n] = z4; }

#pragma unroll
    for (int ks = 0; ks < 4; ++ks) {
        short8 a0 = *(const short8*)&Asz[(w * 32 + p) * KP + ks * 32 + q * 8];
        short8 a1 = *(const short8*)&Asz[(w * 32 + 16 + p) * KP + ks * 32 + q * 8];
        short8 ad = *(const short8*)&drow[ks * 32 + q * 8];   // row-replicated dst A
#pragma unroll
        for (int n = 0; n < 8; ++n) {
            short8 b1 = *(const short8*)&Bsz[(n * 16 + p) * KP + ks * 32 + q * 8];
            short8 b2 = *(const short8*)&W2bf[(n * 16 + p) * DD + ks * 32 + q * 8];
            accS[0][n] = __builtin_amdgcn_mfma_f32_16x16x32_bf16(a0, b1, accS[0][n], 0, 0, 0);
            accS[1][n] = __builtin_amdgcn_mfma_f32_16x16x32_bf16(a1, b1, accS[1][n], 0, 0, 0);
            accD[n]    = __builtin_amdgcn_mfma_f32_16x16x32_bf16(ad, b2, accD[n],    0, 0, 0);
        }
    }

    // epilogue: relu + sum over the node's 32 edges
#pragma unroll
    for (int nt = 0; nt < 8; ++nt) {
        const int col = nt * 16 + p;
        const float base = accD[nt][0] + b_msg[col];   // dst@W2 is row-replicated
        const float w3 = W_msg[col * 257 + 256];
        float sum = 0.f;
#pragma unroll
        for (int m = 0; m < 2; ++m)
#pragma unroll
            for (int r = 0; r < 4; ++r) {
                const int j = m * 16 + q * 4 + r;
                const float val = accS[m][nt][r] + base + s_ef[w * 32 + j] * w3;
                sum += fmaxf(val, 0.f);
            }
        sum += __shfl_xor(sum, 16);
        sum += __shfl_xor(sum, 32);
        if (q == 0) aggbf[(size_t)d * DD + col] = f2bf(sum);
    }
}

// 32 nodes/block, 6 waves (one gate matrix each), frags direct from global (cache-hot)
__global__ __launch_bounds__(384) void gru_kernel(
    const unsigned short* __restrict__ nfbf, const unsigned short* __restrict__ aggbf,
    const unsigned short* __restrict__ wibf, const unsigned short* __restrict__ whbf,
    const float* __restrict__ b_ih, const float* __restrict__ b_hh,
    float* __restrict__ node_sum)
{
    __shared__ float gate_s[6][32][132];
    const int t = threadIdx.x;
    const int n0 = blockIdx.x * 32;
    const int wv = t >> 6, l = t & 63, p = l & 15, q = l >> 4;
    const unsigned short* Wb = (wv < 3) ? wibf : whbf;
    const unsigned short* Ab = (wv < 3) ? aggbf : nfbf;
    const int rowbase = (wv % 3) * 128;

    f32x4 acc[2][8];
    const f32x4 z4 = {0.f, 0.f, 0.f, 0.f};
#pragma unroll
    for (int n = 0; n < 8; ++n) { acc[0][n] = z4; acc[1][n] = z4; }

#pragma unroll
    for (int ks = 0; ks < 4; ++ks) {
        short8 a0 = *(const short8*)&Ab[(size_t)(n0 + p) * DD + ks * 32 + q * 8];
        short8 a1 = *(const short8*)&Ab[(size_t)(n0 + 16 + p) * DD + ks * 32 + q * 8];
#pragma unroll
        for (int n = 0; n < 8; ++n) {
            short8 b = *(const short8*)&Wb[(size_t)(rowbase + n * 16 + p) * DD + ks * 32 + q * 8];
            acc[0][n] = __builtin_amdgcn_mfma_f32_16x16x32_bf16(a0, b, acc[0][n], 0, 0, 0);
            acc[1][n] = __builtin_amdgcn_mfma_f32_16x16x32_bf16(a1, b, acc[1][n], 0, 0, 0);
        }
    }
#pragma unroll
    for (int n = 0; n < 8; ++n)
#pragma unroll
        for (int m = 0; m < 2; ++m)
#pragma unroll
            for (int r = 0; r < 4; ++r)
                gate_s[wv][m * 16 + q * 4 + r][n * 16 + p] = acc[m][n][r];
    __syncthreads();

    const int f = t & 127;
    const int g3 = t >> 7;   // 0..2
    const float bir = b_ih[f], biz = b_ih[128 + f], bin = b_ih[256 + f];
    const float bhr = b_hh[f], bhz = b_hh[128 + f], bhn = b_hh[256 + f];
    float uloc = 0.f;
    for (int j = g3; j < 32; j += 3) {
        const float ir = gate_s[0][j][f], iz = gate_s[1][j][f], inn = gate_s[2][j][f];
        const float hr = gate_s[3][j][f], hz = gate_s[4][j][f], hn = gate_s[5][j][f];
        const float h = bf2f(nfbf[(size_t)(n0 + j) * DD + f]);
        const float r = 1.f / (1.f + expf(-(ir + bir + hr + bhr)));
        const float z = 1.f / (1.f + expf(-(iz + biz + hz + bhz)));
        const float n = tanhf(inn + bin + r * (hn + bhn));
        uloc += (1.f - z) * n + z * h;
    }
    atomicAdd(&node_sum[f], uloc);
}

__global__ void policy_kernel(const float* __restrict__ node_sum,
                              const float* __restrict__ W_pol,
                              const float* __restrict__ b_pol,
                              float* __restrict__ out)
{
    int a = threadIdx.x;
    if (a < AA) {
        float s = b_pol[a];
        for (int k = 0; k < DD; ++k) s += node_sum[k] * W_pol[a * DD + k];
        out[a] = s;
    }
}

extern "C" void kernel_launch(void* const* d_in, const int* in_sizes, int n_in,
                              void* d_out, int out_size, void* d_ws, size_t ws_size,
                              hipStream_t stream)
{
    const float* nf    = (const float*)d_in[0];
    const float* efeat = (const float*)d_in[1];
    const int*   src   = (const int*)d_in[2];
    const int*   dst   = (const int*)d_in[3];
    const float* W_msg = (const float*)d_in[4];
    const float* b_msg = (const float*)d_in[5];
    const float* w_ih  = (const float*)d_in[6];
    const float* w_hh  = (const float*)d_in[7];
    const float* b_ih  = (const float*)d_in[8];
    const float* b_hh  = (const float*)d_in[9];
    const float* W_pol = (const float*)d_in[10];
    const float* b_pol = (const float*)d_in[11];
    float* out = (float*)d_out;

    char* ws = (char*)d_ws;
    int*            inv_src  = (int*)(ws + 0);
    unsigned short* nfbf     = (unsigned short*)(ws + 1048576);
    unsigned short* aggbf    = (unsigned short*)(ws + 3145728);
    float*          node_sum = (float*)(ws + 5242880);
    unsigned short* W1bf     = (unsigned short*)(ws + 5243392);
    unsigned short* W2bf     = (unsigned short*)(ws + 5278208);
    unsigned short* wibf     = (unsigned short*)(ws + 5310976);
    unsigned short* whbf     = (unsigned short*)(ws + 5409280);

    prep_kernel<<<EE / 256, 256, 0, stream>>>(nf, src, dst, W_msg, w_ih, w_hh,
                                              inv_src, nfbf, node_sum,
                                              W1bf, W2bf, wibf, whbf);
    msg_agg_kernel<<<NN / 4, 256, 0, stream>>>(nfbf, efeat, inv_src,
                                               W1bf, W2bf, W_msg, b_msg, aggbf);
    gru_kernel<<<NN / 32, 384, 0, stream>>>(nfbf, aggbf, wibf, whbf,
                                            b_ih, b_hh, node_sum);
    policy_kernel<<<1, 64, 0, stream>>>(node_sum, W_pol, b_pol, out);
}

// Round 4
// 72.381 us; speedup vs baseline: 1.3672x; 1.3672x over previous
//
#include <hip/hip_runtime.h>

#define NN 8192
#define DD 128
#define DEG 32
#define EE (NN*DEG)
#define AA 64

using short8 = __attribute__((ext_vector_type(8))) short;
using f32x4  = __attribute__((ext_vector_type(4))) float;

__device__ __forceinline__ unsigned short f2bf(float x) {
    unsigned u = __builtin_bit_cast(unsigned, x);
    u += 0x7FFFu + ((u >> 16) & 1u);
    return (unsigned short)(u >> 16);
}
__device__ __forceinline__ float bf2f(unsigned short h) {
    unsigned u = ((unsigned)h) << 16;
    return __builtin_bit_cast(float, u);
}

// ---- ws layout (bytes) ----
// inv_src  0         1048576  int  [NN][DEG]
// nfbf     1048576   2097152  bf16 [NN][DD]
// aggbf    3145728   2097152  bf16 [NN][DD]
// node_sum 5242880   512      f32  [DD]
// w3f      5243392   512      f32  [DD]
// W1bf     5243904   32768    bf16 [DD][DD]  (W_msg[:,0:128])
// W2bf     5276672   32768    bf16 [DD][DD]  (W_msg[:,128:256])
// wibf     5309440   98304    bf16 [384][DD]
// whbf     5407744   98304    bf16 [384][DD]
// P        5506048   4194304  f32  [NN][DD]  (nf @ W1^T)
// Q        9700352   4194304  f32  [NN][DD]  (nf @ W2^T + b_msg)
// end      13894656

__global__ __launch_bounds__(256) void prep_kernel(
    const float* __restrict__ nf, const int* __restrict__ src_idx,
    const int* __restrict__ dst_idx,
    const float* __restrict__ W_msg, const float* __restrict__ w_ih,
    const float* __restrict__ w_hh,
    int* __restrict__ inv_src, unsigned short* __restrict__ nfbf,
    float* __restrict__ node_sum, float* __restrict__ w3f,
    unsigned short* __restrict__ W1bf, unsigned short* __restrict__ W2bf,
    unsigned short* __restrict__ wibf, unsigned short* __restrict__ whbf)
{
    const int idx = blockIdx.x * 256 + threadIdx.x;   // 0..EE-1
    {   // slot j = e & 31 is unique per dst for this edge list
        int d = dst_idx[idx];
        inv_src[d * DEG + (idx & 31)] = src_idx[idx];
    }
    {   // nf -> bf16, 4 elems/thread covers NN*DD exactly
        const float4 v = *(const float4*)&nf[(size_t)idx * 4];
        unsigned short h[4] = { f2bf(v.x), f2bf(v.y), f2bf(v.z), f2bf(v.w) };
        *(uint2*)&nfbf[(size_t)idx * 4] = *(uint2*)h;
    }
    if (idx < DD * DD) {
        int f = idx >> 7, k = idx & 127;
        W1bf[idx] = f2bf(W_msg[f * 257 + k]);
        W2bf[idx] = f2bf(W_msg[f * 257 + 128 + k]);
    }
    if (idx < 384 * DD) {
        wibf[idx] = f2bf(w_ih[idx]);
        whbf[idx] = f2bf(w_hh[idx]);
    }
    if (idx < DD) {
        node_sum[idx] = 0.f;
        w3f[idx] = W_msg[idx * 257 + 256];
    }
}

// P = nf@W1^T, Q = nf@W2^T + b_msg ; 128 blocks x 2 waves x 32 rows
__global__ __launch_bounds__(128) void pq_gemm_kernel(
    const unsigned short* __restrict__ nfbf,
    const unsigned short* __restrict__ W1bf, const unsigned short* __restrict__ W2bf,
    const float* __restrict__ b_msg,
    float* __restrict__ P, float* __restrict__ Q)
{
    const int t = threadIdx.x;
    const int w = t >> 6, l = t & 63, p = l & 15, q = l >> 4;
    const int rowbase = blockIdx.x * 64 + w * 32;

    f32x4 accP[2][8], accQ[2][8];
    const f32x4 z4 = {0.f, 0.f, 0.f, 0.f};
#pragma unroll
    for (int m = 0; m < 2; ++m)
#pragma unroll
        for (int n = 0; n < 8; ++n) { accP[m][n] = z4; accQ[m][n] = z4; }

#pragma unroll
    for (int ks = 0; ks < 4; ++ks) {
        short8 a0 = *(const short8*)&nfbf[(size_t)(rowbase + p) * DD + ks * 32 + q * 8];
        short8 a1 = *(const short8*)&nfbf[(size_t)(rowbase + 16 + p) * DD + ks * 32 + q * 8];
#pragma unroll
        for (int n = 0; n < 8; ++n) {
            short8 b1 = *(const short8*)&W1bf[(n * 16 + p) * DD + ks * 32 + q * 8];
            short8 b2 = *(const short8*)&W2bf[(n * 16 + p) * DD + ks * 32 + q * 8];
            accP[0][n] = __builtin_amdgcn_mfma_f32_16x16x32_bf16(a0, b1, accP[0][n], 0, 0, 0);
            accP[1][n] = __builtin_amdgcn_mfma_f32_16x16x32_bf16(a1, b1, accP[1][n], 0, 0, 0);
            accQ[0][n] = __builtin_amdgcn_mfma_f32_16x16x32_bf16(a0, b2, accQ[0][n], 0, 0, 0);
            accQ[1][n] = __builtin_amdgcn_mfma_f32_16x16x32_bf16(a1, b2, accQ[1][n], 0, 0, 0);
        }
    }
#pragma unroll
    for (int n = 0; n < 8; ++n) {
        const int col = n * 16 + p;
        const float bv = b_msg[col];
#pragma unroll
        for (int m = 0; m < 2; ++m)
#pragma unroll
            for (int r = 0; r < 4; ++r) {
                const size_t row = rowbase + m * 16 + q * 4 + r;
                P[row * DD + col] = accP[m][n][r];
                Q[row * DD + col] = accQ[m][n][r] + bv;
            }
    }
}

// agg[d][f] = sum_j relu(P[s_j][f] + Q[d][f] + ef_j * w3[f]) ; 2 nodes/block
__global__ __launch_bounds__(256) void agg_kernel(
    const float* __restrict__ P, const float* __restrict__ Q,
    const float* __restrict__ efeat, const int* __restrict__ inv_src,
    const float* __restrict__ w3f, unsigned short* __restrict__ aggbf)
{
    __shared__ int   s_src[2][DEG];
    __shared__ float s_ef[2][DEG];
    const int t = threadIdx.x;
    const int blk = blockIdx.x;

    if (t < 64) {
        const int dl = t >> 5, j = t & 31;
        const int d = blk * 2 + dl;
        const int s = inv_src[d * DEG + j];
        s_src[dl][j] = s;
        s_ef[dl][j] = efeat[(size_t)s * NN + d];
    }
    __syncthreads();

    const int dl = t >> 7;
    const int f = t & 127;
    const int d = blk * 2 + dl;
    const float base = Q[(size_t)d * DD + f];
    const float w3v = w3f[f];

    float acc = 0.f;
#pragma unroll
    for (int j = 0; j < DEG; ++j) {
        const int s = s_src[dl][j];
        const float v = P[(size_t)s * DD + f] + base + s_ef[dl][j] * w3v;
        acc += fmaxf(v, 0.f);
    }
    aggbf[(size_t)d * DD + f] = f2bf(acc);
}

// 32 nodes/block, 6 waves (one gate matrix each), frags direct from global
__global__ __launch_bounds__(384) void gru_kernel(
    const unsigned short* __restrict__ nfbf, const unsigned short* __restrict__ aggbf,
    const unsigned short* __restrict__ wibf, const unsigned short* __restrict__ whbf,
    const float* __restrict__ b_ih, const float* __restrict__ b_hh,
    float* __restrict__ node_sum)
{
    __shared__ float gate_s[6][32][132];
    const int t = threadIdx.x;
    const int n0 = blockIdx.x * 32;
    const int wv = t >> 6, l = t & 63, p = l & 15, q = l >> 4;
    const unsigned short* Wb = (wv < 3) ? wibf : whbf;
    const unsigned short* Ab = (wv < 3) ? aggbf : nfbf;
    const int rowbase = (wv % 3) * 128;

    f32x4 acc[2][8];
    const f32x4 z4 = {0.f, 0.f, 0.f, 0.f};
#pragma unroll
    for (int n = 0; n < 8; ++n) { acc[0][n] = z4; acc[1][n] = z4; }

#pragma unroll
    for (int ks = 0; ks < 4; ++ks) {
        short8 a0 = *(const short8*)&Ab[(size_t)(n0 + p) * DD + ks * 32 + q * 8];
        short8 a1 = *(const short8*)&Ab[(size_t)(n0 + 16 + p) * DD + ks * 32 + q * 8];
#pragma unroll
        for (int n = 0; n < 8; ++n) {
            short8 b = *(const short8*)&Wb[(size_t)(rowbase + n * 16 + p) * DD + ks * 32 + q * 8];
            acc[0][n] = __builtin_amdgcn_mfma_f32_16x16x32_bf16(a0, b, acc[0][n], 0, 0, 0);
            acc[1][n] = __builtin_amdgcn_mfma_f32_16x16x32_bf16(a1, b, acc[1][n], 0, 0, 0);
        }
    }
#pragma unroll
    for (int n = 0; n < 8; ++n)
#pragma unroll
        for (int m = 0; m < 2; ++m)
#pragma unroll
            for (int r = 0; r < 4; ++r)
                gate_s[wv][m * 16 + q * 4 + r][n * 16 + p] = acc[m][n][r];
    __syncthreads();

    const int f = t & 127;
    const int g3 = t >> 7;   // 0..2
    const float bir = b_ih[f], biz = b_ih[128 + f], bin = b_ih[256 + f];
    const float bhr = b_hh[f], bhz = b_hh[128 + f], bhn = b_hh[256 + f];
    float uloc = 0.f;
    for (int j = g3; j < 32; j += 3) {
        const float ir = gate_s[0][j][f], iz = gate_s[1][j][f], inn = gate_s[2][j][f];
        const float hr = gate_s[3][j][f], hz = gate_s[4][j][f], hn = gate_s[5][j][f];
        const float h = bf2f(nfbf[(size_t)(n0 + j) * DD + f]);
        const float r = 1.f / (1.f + expf(-(ir + bir + hr + bhr)));
        const float z = 1.f / (1.f + expf(-(iz + biz + hz + bhz)));
        const float n = tanhf(inn + bin + r * (hn + bhn));
        uloc += (1.f - z) * n + z * h;
    }
    atomicAdd(&node_sum[f], uloc);
}

__global__ void policy_kernel(const float* __restrict__ node_sum,
                              const float* __restrict__ W_pol,
                              const float* __restrict__ b_pol,
                              float* __restrict__ out)
{
    int a = threadIdx.x;
    if (a < AA) {
        float s = b_pol[a];
        for (int k = 0; k < DD; ++k) s += node_sum[k] * W_pol[a * DD + k];
        out[a] = s;
    }
}

extern "C" void kernel_launch(void* const* d_in, const int* in_sizes, int n_in,
                              void* d_out, int out_size, void* d_ws, size_t ws_size,
                              hipStream_t stream)
{
    const float* nf    = (const float*)d_in[0];
    const float* efeat = (const float*)d_in[1];
    const int*   src   = (const int*)d_in[2];
    const int*   dst   = (const int*)d_in[3];
    const float* W_msg = (const float*)d_in[4];
    const float* b_msg = (const float*)d_in[5];
    const float* w_ih  = (const float*)d_in[6];
    const float* w_hh  = (const float*)d_in[7];
    const float* b_ih  = (const float*)d_in[8];
    const float* b_hh  = (const float*)d_in[9];
    const float* W_pol = (const float*)d_in[10];
    const float* b_pol = (const float*)d_in[11];
    float* out = (float*)d_out;

    char* ws = (char*)d_ws;
    int*            inv_src  = (int*)(ws + 0);
    unsigned short* nfbf     = (unsigned short*)(ws + 1048576);
    unsigned short* aggbf    = (unsigned short*)(ws + 3145728);
    float*          node_sum = (float*)(ws + 5242880);
    float*          w3f      = (float*)(ws + 5243392);
    unsigned short* W1bf     = (unsigned short*)(ws + 5243904);
    unsigned short* W2bf     = (unsigned short*)(ws + 5276672);
    unsigned short* wibf     = (unsigned short*)(ws + 5309440);
    unsigned short* whbf     = (unsigned short*)(ws + 5407744);
    float*          P        = (float*)(ws + 5506048);
    float*          Q        = (float*)(ws + 9700352);

    prep_kernel<<<EE / 256, 256, 0, stream>>>(nf, src, dst, W_msg, w_ih, w_hh,
                                              inv_src, nfbf, node_sum, w3f,
                                              W1bf, W2bf, wibf, whbf);
    pq_gemm_kernel<<<128, 128, 0, stream>>>(nfbf, W1bf, W2bf, b_msg, P, Q);
    agg_kernel<<<NN / 2, 256, 0, stream>>>(P, Q, efeat, inv_src, w3f, aggbf);
    gru_kernel<<<NN / 32, 384, 0, stream>>>(nfbf, aggbf, wibf, whbf,
                                            b_ih, b_hh, node_sum);
    policy_kernel<<<1, 64, 0, stream>>>(node_sum, W_pol, b_pol, out);
}